// Round 1
// baseline (4436.589 us; speedup 1.0000x reference)
//
#include <hip/hip_runtime.h>
#include <math.h>

#define NNODES  100000
#define NEDGES  3200000
#define NGRAPHS 1024

// ---------------- zero / init ----------------

__global__ void zero4_kernel(float4* p, int nvec) {
    int i = blockIdx.x * blockDim.x + threadIdx.x;
    if (i < nvec) p[i] = make_float4(0.f, 0.f, 0.f, 0.f);
}

__global__ void deg_init_kernel(float* deg) {
    int i = blockIdx.x * blockDim.x + threadIdx.x;
    if (i < NNODES) deg[i] = 1.0f;  // self-loop
}

__global__ void degree_kernel(const int* __restrict__ dst, float* __restrict__ deg) {
    int e = blockIdx.x * blockDim.x + threadIdx.x;
    if (e < NEDGES) atomicAdd(&deg[dst[e]], 1.0f);
}

__global__ void rsqrt_kernel(float* deg) {
    int i = blockIdx.x * blockDim.x + threadIdx.x;
    if (i < NNODES) deg[i] = rsqrtf(deg[i]);  // deg >= 1 always (self-loop)
}

// ---------------- dense node GEMMs ----------------

// hm1[n][j] = sum_k x[n][k] * W1[k][j]   (N x 16) @ (16 x 64)
__global__ void gemm1_kernel(const float* __restrict__ x, const float* __restrict__ W1,
                             float* __restrict__ hm1) {
    __shared__ float w[16 * 64];
    for (int i = threadIdx.x; i < 16 * 64; i += blockDim.x) w[i] = W1[i];
    __syncthreads();
    int t = blockIdx.x * blockDim.x + threadIdx.x;
    if (t >= NNODES * 64) return;
    int n = t >> 6, j = t & 63;
    const float* xr = x + n * 16;
    float acc = 0.f;
#pragma unroll
    for (int k = 0; k < 16; ++k) acc += xr[k] * w[k * 64 + j];
    hm1[t] = acc;
}

// hm2[n][j] = sum_k h1[n][k] * W2[k][j]  (N x 64) @ (64 x 32)
__global__ void gemm2_kernel(const float* __restrict__ h1, const float* __restrict__ W2,
                             float* __restrict__ hm2) {
    __shared__ float w[64 * 32];
    for (int i = threadIdx.x; i < 64 * 32; i += blockDim.x) w[i] = W2[i];
    __syncthreads();
    int t = blockIdx.x * blockDim.x + threadIdx.x;
    if (t >= NNODES * 32) return;
    int n = t >> 5, j = t & 31;
    const float* hr = h1 + n * 64;
    float acc = 0.f;
#pragma unroll
    for (int k = 0; k < 64; ++k) acc += hr[k] * w[k * 32 + j];
    hm2[t] = acc;
}

// ---------------- edge scatter ----------------

// 16 threads per edge, each does one float4 chunk of the 64-float row
__global__ void scatter1_kernel(const int* __restrict__ src, const int* __restrict__ dst,
                                const float* __restrict__ dinv,
                                const float4* __restrict__ hm1, float* __restrict__ acc1) {
    int t = blockIdx.x * blockDim.x + threadIdx.x;
    if (t >= NEDGES * 16) return;
    int e = t >> 4, c = t & 15;
    int s = src[e], d = dst[e];
    float w = dinv[s] * dinv[d];
    float4 v = hm1[s * 16 + c];
    float* out = acc1 + (size_t)d * 64 + c * 4;
    atomicAdd(out + 0, v.x * w);
    atomicAdd(out + 1, v.y * w);
    atomicAdd(out + 2, v.z * w);
    atomicAdd(out + 3, v.w * w);
}

// 8 threads per edge, 32-float rows
__global__ void scatter2_kernel(const int* __restrict__ src, const int* __restrict__ dst,
                                const float* __restrict__ dinv,
                                const float4* __restrict__ hm2, float* __restrict__ acc2) {
    int t = blockIdx.x * blockDim.x + threadIdx.x;
    if (t >= NEDGES * 8) return;
    int e = t >> 3, c = t & 7;
    int s = src[e], d = dst[e];
    float w = dinv[s] * dinv[d];
    float4 v = hm2[s * 8 + c];
    float* out = acc2 + (size_t)d * 32 + c * 4;
    atomicAdd(out + 0, v.x * w);
    atomicAdd(out + 1, v.y * w);
    atomicAdd(out + 2, v.z * w);
    atomicAdd(out + 3, v.w * w);
}

// ---------------- epilogues ----------------

// h1 = relu(acc1 + hm1*dinv^2 + b1), in place into acc1. (self-loop applied here)
__global__ void bias_relu1_kernel(float* __restrict__ acc1, const float* __restrict__ hm1,
                                  const float* __restrict__ dinv, const float* __restrict__ b1) {
    int t = blockIdx.x * blockDim.x + threadIdx.x;
    if (t >= NNODES * 64) return;
    int n = t >> 6, j = t & 63;
    float di = dinv[n];
    float v = acc1[t] + hm1[t] * di * di + b1[j];
    acc1[t] = fmaxf(v, 0.f);
}

// h2 = relu(acc2 + hm2*dinv^2 + b2); pool-atomics into psum/pcnt (batch sorted, contention ok)
__global__ void relu_pool_kernel(const float* __restrict__ acc2, const float* __restrict__ hm2,
                                 const float* __restrict__ dinv, const float* __restrict__ b2,
                                 const int* __restrict__ batch,
                                 float* __restrict__ psum, float* __restrict__ pcnt) {
    int t = blockIdx.x * blockDim.x + threadIdx.x;
    if (t >= NNODES * 32) return;
    int n = t >> 5, j = t & 31;
    float di = dinv[n];
    float v = fmaxf(acc2[t] + hm2[t] * di * di + b2[j], 0.f);
    int g = batch[n];
    atomicAdd(&psum[(size_t)g * 32 + j], v);
    if (j == 0) atomicAdd(&pcnt[g], 1.0f);
}

// per-graph MLP head: g = psum/cnt -> fc1 relu -> fc2 -> sigmoid
__global__ void head_kernel(const float* __restrict__ psum, const float* __restrict__ pcnt,
                            const float* __restrict__ fc1W, const float* __restrict__ fc1b,
                            const float* __restrict__ fc2W, const float* __restrict__ fc2b,
                            float* __restrict__ out) {
    int g = blockIdx.x * blockDim.x + threadIdx.x;
    if (g >= NGRAPHS) return;
    float inv = 1.0f / fmaxf(pcnt[g], 1.0f);
    float gv[32];
#pragma unroll
    for (int k = 0; k < 32; ++k) gv[k] = psum[g * 32 + k] * inv;
    float o = fc2b[0];
#pragma unroll
    for (int j = 0; j < 16; ++j) {
        float h = fc1b[j];
#pragma unroll
        for (int k = 0; k < 32; ++k) h += gv[k] * fc1W[k * 16 + j];
        h = fmaxf(h, 0.f);
        o += h * fc2W[j];
    }
    out[g] = 1.0f / (1.0f + expf(-o));
}

// ---------------- launch ----------------

extern "C" void kernel_launch(void* const* d_in, const int* in_sizes, int n_in,
                              void* d_out, int out_size, void* d_ws, size_t ws_size,
                              hipStream_t stream) {
    const float* x    = (const float*)d_in[0];
    const int*   ei   = (const int*)d_in[1];   // [2, NEDGES]: row0 = src, row1 = dst
    const int*   batch= (const int*)d_in[2];
    const float* W1   = (const float*)d_in[3];
    const float* b1   = (const float*)d_in[4];
    const float* W2   = (const float*)d_in[5];
    const float* b2   = (const float*)d_in[6];
    const float* fc1W = (const float*)d_in[7];
    const float* fc1b = (const float*)d_in[8];
    const float* fc2W = (const float*)d_in[9];
    const float* fc2b = (const float*)d_in[10];
    float* out = (float*)d_out;

    const int* src = ei;
    const int* dst = ei + NEDGES;

    float* ws   = (float*)d_ws;
    float* deg  = ws;                    // N (becomes dinv)
    float* hm1  = ws + 100352;           // N*64
    float* hm2  = hm1 + NNODES * 64;     // N*32
    float* acc1 = hm2 + NNODES * 32;     // N*64   } zeroed span
    float* acc2 = acc1 + NNODES * 64;    // N*32   }
    float* psum = acc2 + NNODES * 32;    // 32768  }
    float* pcnt = psum + NGRAPHS * 32;   // 1024   }

    const int B = 256;
    const int zero_span = NNODES * 64 + NNODES * 32 + NGRAPHS * 32 + NGRAPHS;  // floats
    const int zero_vec = zero_span / 4;

    zero4_kernel<<<(zero_vec + B - 1) / B, B, 0, stream>>>((float4*)acc1, zero_vec);
    deg_init_kernel<<<(NNODES + B - 1) / B, B, 0, stream>>>(deg);
    degree_kernel<<<(NEDGES + B - 1) / B, B, 0, stream>>>(dst, deg);
    rsqrt_kernel<<<(NNODES + B - 1) / B, B, 0, stream>>>(deg);

    gemm1_kernel<<<(NNODES * 64 + B - 1) / B, B, 0, stream>>>(x, W1, hm1);
    scatter1_kernel<<<(NEDGES * 16 + B - 1) / B, B, 0, stream>>>(src, dst, deg, (const float4*)hm1, acc1);
    bias_relu1_kernel<<<(NNODES * 64 + B - 1) / B, B, 0, stream>>>(acc1, hm1, deg, b1);

    gemm2_kernel<<<(NNODES * 32 + B - 1) / B, B, 0, stream>>>(acc1, W2, hm2);
    scatter2_kernel<<<(NEDGES * 8 + B - 1) / B, B, 0, stream>>>(src, dst, deg, (const float4*)hm2, acc2);
    relu_pool_kernel<<<(NNODES * 32 + B - 1) / B, B, 0, stream>>>(acc2, hm2, deg, b2, batch, psum, pcnt);

    head_kernel<<<(NGRAPHS + B - 1) / B, B, 0, stream>>>(psum, pcnt, fc1W, fc1b, fc2W, fc2b, out);
}

// Round 2
// 806.051 us; speedup vs baseline: 5.5041x; 5.5041x over previous
//
#include <hip/hip_runtime.h>
#include <math.h>

#define NNODES  100000
#define NEDGES  3200000
#define NGRAPHS 1024
#define NBLK    ((NNODES + 255) / 256)   // 391 scan blocks

// ---------------- init ----------------

__global__ void zero4_kernel(int4* p, int nvec) {
    int i = blockIdx.x * blockDim.x + threadIdx.x;
    if (i < nvec) p[i] = make_int4(0, 0, 0, 0);
}

// histogram of dst (in-degree, excluding self-loop)
__global__ void hist_kernel(const int* __restrict__ dst, int* __restrict__ cnt) {
    int e = blockIdx.x * blockDim.x + threadIdx.x;
    if (e < NEDGES) atomicAdd(&cnt[dst[e]], 1);
}

__global__ void dinv_kernel(const int* __restrict__ cnt, float* __restrict__ dinv) {
    int i = blockIdx.x * blockDim.x + threadIdx.x;
    if (i < NNODES) dinv[i] = rsqrtf((float)(cnt[i] + 1));  // +1 self-loop
}

// ---------------- exclusive scan (3 kernels) ----------------

__global__ void scanA_kernel(const int* __restrict__ cnt, int* __restrict__ part,
                             int* __restrict__ bsum) {
    __shared__ int s[256];
    int i = blockIdx.x * 256 + threadIdx.x;
    int v = (i < NNODES) ? cnt[i] : 0;
    s[threadIdx.x] = v;
    __syncthreads();
    for (int off = 1; off < 256; off <<= 1) {
        int t = (threadIdx.x >= off) ? s[threadIdx.x - off] : 0;
        __syncthreads();
        s[threadIdx.x] += t;
        __syncthreads();
    }
    int incl = s[threadIdx.x];
    if (i < NNODES) part[i] = incl - v;            // exclusive within block
    if (threadIdx.x == 255) bsum[blockIdx.x] = incl;
}

__global__ void scanB_kernel(int* __restrict__ bsum, int* __restrict__ boff) {
    if (threadIdx.x == 0 && blockIdx.x == 0) {
        int run = 0;
        for (int i = 0; i < NBLK; ++i) { boff[i] = run; run += bsum[i]; }
    }
}

__global__ void scanC_kernel(int* __restrict__ part, const int* __restrict__ boff,
                             int* __restrict__ rowptr, int* __restrict__ cursor) {
    int i = blockIdx.x * 256 + threadIdx.x;
    if (i < NNODES) {
        int v = part[i] + boff[blockIdx.x];
        rowptr[i] = v;
        cursor[i] = v;
    }
}

// ---------------- CSR fill ----------------

// entries[slot] = {src, norm}; cursor[n] ends as rowend[n]
__global__ void csr_fill_kernel(const int* __restrict__ src, const int* __restrict__ dst,
                                const float* __restrict__ dinv, int* __restrict__ cursor,
                                int2* __restrict__ entries) {
    int e = blockIdx.x * blockDim.x + threadIdx.x;
    if (e >= NEDGES) return;
    int s = src[e], d = dst[e];
    int slot = atomicAdd(&cursor[d], 1);
    float nrm = dinv[s] * dinv[d];
    entries[slot] = make_int2(s, __float_as_int(nrm));
}

// ---------------- gathers ----------------

// ax[n][f] = sum_{e in(n)} x[src_e][f]*norm_e + x[n][f]*dinv[n]^2   (16-wide)
__global__ void gather1_kernel(const int2* __restrict__ entries, const int* __restrict__ rowptr,
                               const int* __restrict__ rowend, const float* __restrict__ dinv,
                               const float* __restrict__ x, float* __restrict__ ax) {
    int t = blockIdx.x * blockDim.x + threadIdx.x;
    int n = t >> 4, lane = t & 15;
    if (n >= NNODES) return;
    int beg = rowptr[n], end = rowend[n];
    float di = dinv[n];
    float acc = x[n * 16 + lane] * di * di;
    for (int e = beg; e < end; ++e) {
        int2 en = entries[e];
        acc += x[en.x * 16 + lane] * __int_as_float(en.y);
    }
    ax[n * 16 + lane] = acc;
}

// h2[n][lane] then pooled: 32 lanes per node
__global__ void gather2_pool_kernel(const int2* __restrict__ entries, const int* __restrict__ rowptr,
                                    const int* __restrict__ rowend, const float* __restrict__ dinv,
                                    const float* __restrict__ hm2, const float* __restrict__ b2,
                                    const int* __restrict__ batch,
                                    float* __restrict__ psum, float* __restrict__ pcnt) {
    int t = blockIdx.x * blockDim.x + threadIdx.x;
    int n = t >> 5, lane = t & 31;
    if (n >= NNODES) return;
    int beg = rowptr[n], end = rowend[n];
    float di = dinv[n];
    float acc = hm2[n * 32 + lane] * di * di;
    for (int e = beg; e < end; ++e) {
        int2 en = entries[e];
        acc += hm2[en.x * 32 + lane] * __int_as_float(en.y);
    }
    float v = fmaxf(acc + b2[lane], 0.f);
    int g = batch[n];
    atomicAdd(&psum[g * 32 + lane], v);
    if (lane == 0) atomicAdd(&pcnt[g], 1.0f);
}

// ---------------- dense GEMMs ----------------

// h1 = relu(ax @ W1 + b1)   (N x 16) @ (16 x 64)
__global__ void gemm1_kernel(const float* __restrict__ ax, const float* __restrict__ W1,
                             const float* __restrict__ b1, float* __restrict__ h1) {
    __shared__ float w[16 * 64];
    __shared__ float bb[64];
    for (int i = threadIdx.x; i < 16 * 64; i += blockDim.x) w[i] = W1[i];
    if (threadIdx.x < 64) bb[threadIdx.x] = b1[threadIdx.x];
    __syncthreads();
    int t = blockIdx.x * blockDim.x + threadIdx.x;
    if (t >= NNODES * 64) return;
    int n = t >> 6, j = t & 63;
    const float* xr = ax + n * 16;
    float acc = bb[j];
#pragma unroll
    for (int k = 0; k < 16; ++k) acc += xr[k] * w[k * 64 + j];
    h1[t] = fmaxf(acc, 0.f);
}

// hm2 = h1 @ W2   (N x 64) @ (64 x 32)
__global__ void gemm2_kernel(const float* __restrict__ h1, const float* __restrict__ W2,
                             float* __restrict__ hm2) {
    __shared__ float w[64 * 32];
    for (int i = threadIdx.x; i < 64 * 32; i += blockDim.x) w[i] = W2[i];
    __syncthreads();
    int t = blockIdx.x * blockDim.x + threadIdx.x;
    if (t >= NNODES * 32) return;
    int n = t >> 5, j = t & 31;
    const float* hr = h1 + n * 64;
    float acc = 0.f;
#pragma unroll
    for (int k = 0; k < 64; ++k) acc += hr[k] * w[k * 32 + j];
    hm2[t] = acc;
}

// ---------------- head ----------------

__global__ void head_kernel(const float* __restrict__ psum, const float* __restrict__ pcnt,
                            const float* __restrict__ fc1W, const float* __restrict__ fc1b,
                            const float* __restrict__ fc2W, const float* __restrict__ fc2b,
                            float* __restrict__ out) {
    int g = blockIdx.x * blockDim.x + threadIdx.x;
    if (g >= NGRAPHS) return;
    float inv = 1.0f / fmaxf(pcnt[g], 1.0f);
    float gv[32];
#pragma unroll
    for (int k = 0; k < 32; ++k) gv[k] = psum[g * 32 + k] * inv;
    float o = fc2b[0];
#pragma unroll
    for (int j = 0; j < 16; ++j) {
        float h = fc1b[j];
#pragma unroll
        for (int k = 0; k < 32; ++k) h += gv[k] * fc1W[k * 16 + j];
        h = fmaxf(h, 0.f);
        o += h * fc2W[j];
    }
    out[g] = 1.0f / (1.0f + expf(-o));
}

// ---------------- launch ----------------

extern "C" void kernel_launch(void* const* d_in, const int* in_sizes, int n_in,
                              void* d_out, int out_size, void* d_ws, size_t ws_size,
                              hipStream_t stream) {
    const float* x    = (const float*)d_in[0];
    const int*   ei   = (const int*)d_in[1];
    const int*   batch= (const int*)d_in[2];
    const float* W1   = (const float*)d_in[3];
    const float* b1   = (const float*)d_in[4];
    const float* W2   = (const float*)d_in[5];
    const float* b2   = (const float*)d_in[6];
    const float* fc1W = (const float*)d_in[7];
    const float* fc1b = (const float*)d_in[8];
    const float* fc2W = (const float*)d_in[9];
    const float* fc2b = (const float*)d_in[10];
    float* out = (float*)d_out;

    const int* src = ei;
    const int* dst = ei + NEDGES;

    // workspace layout (units of 4 B)
    char* wsb = (char*)d_ws;
    int*   cnt    = (int*)wsb;                           // [0, 100000)   — zeroed
    float* psum   = (float*)(wsb + 400000);              // 32768 floats  — zeroed
    float* pcnt   = (float*)(wsb + 531072);              // 1024 floats   — zeroed
    float* dinv   = (float*)(wsb + 535168);              // 100000
    int*   rowptr = (int*)(wsb + 935168);                // 100000
    int*   cursor = (int*)(wsb + 1335168);               // 100000
    int*   bsum   = (int*)(wsb + 1735168);               // 391
    int*   boff   = (int*)(wsb + 1736736);               // 391 (8B-aligned)
    int2*  entries= (int2*)(wsb + 1738304);              // 3.2M int2 = 25.6 MB (8B-aligned)
    float* ax     = (float*)(wsb + 27338304);            // N*16
    float* h1     = (float*)(wsb + 33738304);            // N*64
    float* hm2    = (float*)(wsb + 59338304);            // N*32  (ends at 72,138,304 B)

    const int B = 256;
    // zero cnt + psum + pcnt: contiguous span of 133792 ints = 33448 int4
    zero4_kernel<<<(33448 + B - 1) / B, B, 0, stream>>>((int4*)cnt, 33448);

    hist_kernel<<<(NEDGES + B - 1) / B, B, 0, stream>>>(dst, cnt);
    dinv_kernel<<<(NNODES + B - 1) / B, B, 0, stream>>>(cnt, dinv);

    scanA_kernel<<<NBLK, 256, 0, stream>>>(cnt, rowptr, bsum);
    scanB_kernel<<<1, 64, 0, stream>>>(bsum, boff);
    scanC_kernel<<<NBLK, 256, 0, stream>>>(rowptr, boff, rowptr, cursor);

    csr_fill_kernel<<<(NEDGES + B - 1) / B, B, 0, stream>>>(src, dst, dinv, cursor, entries);

    gather1_kernel<<<(NNODES * 16 + B - 1) / B, B, 0, stream>>>(entries, rowptr, cursor, dinv, x, ax);
    gemm1_kernel<<<(NNODES * 64 + B - 1) / B, B, 0, stream>>>(ax, W1, b1, h1);
    gemm2_kernel<<<(NNODES * 32 + B - 1) / B, B, 0, stream>>>(h1, W2, hm2);
    gather2_pool_kernel<<<(NNODES * 32 + B - 1) / B, B, 0, stream>>>(entries, rowptr, cursor, dinv,
                                                                     hm2, b2, batch, psum, pcnt);
    head_kernel<<<(NGRAPHS + B - 1) / B, B, 0, stream>>>(psum, pcnt, fc1W, fc1b, fc2W, fc2b, out);
}

// Round 3
// 688.304 us; speedup vs baseline: 6.4457x; 1.1711x over previous
//
#include <hip/hip_runtime.h>
#include <math.h>

#define NNODES  100000
#define NEDGES  3200000
#define NGRAPHS 1024
#define NBLK    ((NNODES + 255) / 256)   // 391 scan blocks

// ---------------- init ----------------

__global__ void zero4_kernel(int4* p, int nvec) {
    int i = blockIdx.x * blockDim.x + threadIdx.x;
    if (i < nvec) p[i] = make_int4(0, 0, 0, 0);
}

// histogram of dst (in-degree, excluding self-loop)
__global__ void hist_kernel(const int* __restrict__ dst, int* __restrict__ cnt) {
    int e = blockIdx.x * blockDim.x + threadIdx.x;
    if (e < NEDGES) atomicAdd(&cnt[dst[e]], 1);
}

__global__ void dinv_kernel(const int* __restrict__ cnt, float* __restrict__ dinv) {
    int i = blockIdx.x * blockDim.x + threadIdx.x;
    if (i < NNODES) dinv[i] = rsqrtf((float)(cnt[i] + 1));  // +1 self-loop
}

// ---------------- exclusive scan (3 kernels) ----------------

__global__ void scanA_kernel(const int* __restrict__ cnt, int* __restrict__ part,
                             int* __restrict__ bsum) {
    __shared__ int s[256];
    int i = blockIdx.x * 256 + threadIdx.x;
    int v = (i < NNODES) ? cnt[i] : 0;
    s[threadIdx.x] = v;
    __syncthreads();
    for (int off = 1; off < 256; off <<= 1) {
        int t = (threadIdx.x >= off) ? s[threadIdx.x - off] : 0;
        __syncthreads();
        s[threadIdx.x] += t;
        __syncthreads();
    }
    int incl = s[threadIdx.x];
    if (i < NNODES) part[i] = incl - v;            // exclusive within block
    if (threadIdx.x == 255) bsum[blockIdx.x] = incl;
}

__global__ void scanB_kernel(int* __restrict__ bsum, int* __restrict__ boff) {
    if (threadIdx.x == 0 && blockIdx.x == 0) {
        int run = 0;
        for (int i = 0; i < NBLK; ++i) { boff[i] = run; run += bsum[i]; }
    }
}

__global__ void scanC_kernel(int* __restrict__ part, const int* __restrict__ boff,
                             int* __restrict__ rowptr, int* __restrict__ cursor) {
    int i = blockIdx.x * 256 + threadIdx.x;
    if (i < NNODES) {
        int v = part[i] + boff[blockIdx.x];
        rowptr[i] = v;
        cursor[i] = v;
    }
}

// ---------------- CSR fill ----------------

__global__ void csr_fill_kernel(const int* __restrict__ src, const int* __restrict__ dst,
                                const float* __restrict__ dinv, int* __restrict__ cursor,
                                int2* __restrict__ entries) {
    int e = blockIdx.x * blockDim.x + threadIdx.x;
    if (e >= NEDGES) return;
    int s = src[e], d = dst[e];
    int slot = atomicAdd(&cursor[d], 1);
    float nrm = dinv[s] * dinv[d];
    entries[slot] = make_int2(s, __float_as_int(nrm));
}

// ---------------- gathers (chunked shfl-broadcast) ----------------

// ax[n][f] = sum_in x[src][f]*norm + x[n][f]*dinv^2   — 16 lanes/node
__global__ void gather1_kernel(const int2* __restrict__ entries, const int* __restrict__ rowptr,
                               const int* __restrict__ rowend, const float* __restrict__ dinv,
                               const float* __restrict__ x, float* __restrict__ ax) {
    int t = blockIdx.x * blockDim.x + threadIdx.x;
    int n = t >> 4, lane = t & 15;
    if (n >= NNODES) return;
    int beg = rowptr[n], end = rowend[n];
    float di = dinv[n];
    float acc = x[n * 16 + lane] * di * di;
    for (int base = beg; base < end; base += 16) {
        int m = end - base; if (m > 16) m = 16;
        int2 en = (lane < m) ? entries[base + lane] : make_int2(0, 0);
        if (m == 16) {
#pragma unroll
            for (int j = 0; j < 16; ++j) {
                int s = __shfl(en.x, j, 16);
                float nrm = __shfl(__int_as_float(en.y), j, 16);
                acc += x[s * 16 + lane] * nrm;
            }
        } else {
            for (int j = 0; j < m; ++j) {
                int s = __shfl(en.x, j, 16);
                float nrm = __shfl(__int_as_float(en.y), j, 16);
                acc += x[s * 16 + lane] * nrm;
            }
        }
    }
    ax[n * 16 + lane] = acc;
}

// h2 row then pool — 32 lanes/node
__global__ void gather2_pool_kernel(const int2* __restrict__ entries, const int* __restrict__ rowptr,
                                    const int* __restrict__ rowend, const float* __restrict__ dinv,
                                    const float* __restrict__ hm2, const float* __restrict__ b2,
                                    const int* __restrict__ batch,
                                    float* __restrict__ psum, float* __restrict__ pcnt) {
    int t = blockIdx.x * blockDim.x + threadIdx.x;
    int n = t >> 5, lane = t & 31;
    if (n >= NNODES) return;
    int beg = rowptr[n], end = rowend[n];
    float di = dinv[n];
    float acc = hm2[n * 32 + lane] * di * di;
    for (int base = beg; base < end; base += 32) {
        int m = end - base; if (m > 32) m = 32;
        int2 en = (lane < m) ? entries[base + lane] : make_int2(0, 0);
        if (m == 32) {
#pragma unroll 16
            for (int j = 0; j < 32; ++j) {
                int s = __shfl(en.x, j, 32);
                float nrm = __shfl(__int_as_float(en.y), j, 32);
                acc += hm2[s * 32 + lane] * nrm;
            }
        } else {
            for (int j = 0; j < m; ++j) {
                int s = __shfl(en.x, j, 32);
                float nrm = __shfl(__int_as_float(en.y), j, 32);
                acc += hm2[s * 32 + lane] * nrm;
            }
        }
    }
    float v = fmaxf(acc + b2[lane], 0.f);
    int g = batch[n];
    atomicAdd(&psum[g * 32 + lane], v);
    if (lane == 0) atomicAdd(&pcnt[g], 1.0f);
}

// ---------------- dense GEMMs ----------------

__global__ void gemm1_kernel(const float* __restrict__ ax, const float* __restrict__ W1,
                             const float* __restrict__ b1, float* __restrict__ h1) {
    __shared__ float w[16 * 64];
    __shared__ float bb[64];
    for (int i = threadIdx.x; i < 16 * 64; i += blockDim.x) w[i] = W1[i];
    if (threadIdx.x < 64) bb[threadIdx.x] = b1[threadIdx.x];
    __syncthreads();
    int t = blockIdx.x * blockDim.x + threadIdx.x;
    if (t >= NNODES * 64) return;
    int n = t >> 6, j = t & 63;
    const float* xr = ax + n * 16;
    float acc = bb[j];
#pragma unroll
    for (int k = 0; k < 16; ++k) acc += xr[k] * w[k * 64 + j];
    h1[t] = fmaxf(acc, 0.f);
}

__global__ void gemm2_kernel(const float* __restrict__ h1, const float* __restrict__ W2,
                             float* __restrict__ hm2) {
    __shared__ float w[64 * 32];
    for (int i = threadIdx.x; i < 64 * 32; i += blockDim.x) w[i] = W2[i];
    __syncthreads();
    int t = blockIdx.x * blockDim.x + threadIdx.x;
    if (t >= NNODES * 32) return;
    int n = t >> 5, j = t & 31;
    const float* hr = h1 + n * 64;
    float acc = 0.f;
#pragma unroll
    for (int k = 0; k < 64; ++k) acc += hr[k] * w[k * 32 + j];
    hm2[t] = acc;
}

// ---------------- head ----------------

__global__ void head_kernel(const float* __restrict__ psum, const float* __restrict__ pcnt,
                            const float* __restrict__ fc1W, const float* __restrict__ fc1b,
                            const float* __restrict__ fc2W, const float* __restrict__ fc2b,
                            float* __restrict__ out) {
    int g = blockIdx.x * blockDim.x + threadIdx.x;
    if (g >= NGRAPHS) return;
    float inv = 1.0f / fmaxf(pcnt[g], 1.0f);
    float gv[32];
#pragma unroll
    for (int k = 0; k < 32; ++k) gv[k] = psum[g * 32 + k] * inv;
    float o = fc2b[0];
#pragma unroll
    for (int j = 0; j < 16; ++j) {
        float h = fc1b[j];
#pragma unroll
        for (int k = 0; k < 32; ++k) h += gv[k] * fc1W[k * 16 + j];
        h = fmaxf(h, 0.f);
        o += h * fc2W[j];
    }
    out[g] = 1.0f / (1.0f + expf(-o));
}

// ---------------- launch ----------------

extern "C" void kernel_launch(void* const* d_in, const int* in_sizes, int n_in,
                              void* d_out, int out_size, void* d_ws, size_t ws_size,
                              hipStream_t stream) {
    const float* x    = (const float*)d_in[0];
    const int*   ei   = (const int*)d_in[1];
    const int*   batch= (const int*)d_in[2];
    const float* W1   = (const float*)d_in[3];
    const float* b1   = (const float*)d_in[4];
    const float* W2   = (const float*)d_in[5];
    const float* b2   = (const float*)d_in[6];
    const float* fc1W = (const float*)d_in[7];
    const float* fc1b = (const float*)d_in[8];
    const float* fc2W = (const float*)d_in[9];
    const float* fc2b = (const float*)d_in[10];
    float* out = (float*)d_out;

    const int* src = ei;
    const int* dst = ei + NEDGES;

    char* wsb = (char*)d_ws;
    int*   cnt    = (int*)wsb;                           // 100000 — zeroed
    float* psum   = (float*)(wsb + 400000);              // 32768  — zeroed
    float* pcnt   = (float*)(wsb + 531072);              // 1024   — zeroed
    float* dinv   = (float*)(wsb + 535168);              // 100000
    int*   rowptr = (int*)(wsb + 935168);                // 100000
    int*   cursor = (int*)(wsb + 1335168);               // 100000
    int*   bsum   = (int*)(wsb + 1735168);               // 391
    int*   boff   = (int*)(wsb + 1736736);               // 391
    int2*  entries= (int2*)(wsb + 1738304);              // 3.2M int2 (8B-aligned)
    float* ax     = (float*)(wsb + 27338304);            // N*16
    float* h1     = (float*)(wsb + 33738304);            // N*64
    float* hm2    = (float*)(wsb + 59338304);            // N*32

    const int B = 256;
    zero4_kernel<<<(33448 + B - 1) / B, B, 0, stream>>>((int4*)cnt, 33448);

    hist_kernel<<<(NEDGES + B - 1) / B, B, 0, stream>>>(dst, cnt);
    dinv_kernel<<<(NNODES + B - 1) / B, B, 0, stream>>>(cnt, dinv);

    scanA_kernel<<<NBLK, 256, 0, stream>>>(cnt, rowptr, bsum);
    scanB_kernel<<<1, 64, 0, stream>>>(bsum, boff);
    scanC_kernel<<<NBLK, 256, 0, stream>>>(rowptr, boff, rowptr, cursor);

    csr_fill_kernel<<<(NEDGES + B - 1) / B, B, 0, stream>>>(src, dst, dinv, cursor, entries);

    gather1_kernel<<<(NNODES * 16 + B - 1) / B, B, 0, stream>>>(entries, rowptr, cursor, dinv, x, ax);
    gemm1_kernel<<<(NNODES * 64 + B - 1) / B, B, 0, stream>>>(ax, W1, b1, h1);
    gemm2_kernel<<<(NNODES * 32 + B - 1) / B, B, 0, stream>>>(h1, W2, hm2);
    gather2_pool_kernel<<<(NNODES * 32 + B - 1) / B, B, 0, stream>>>(entries, rowptr, cursor, dinv,
                                                                     hm2, b2, batch, psum, pcnt);
    head_kernel<<<(NGRAPHS + B - 1) / B, B, 0, stream>>>(psum, pcnt, fc1W, fc1b, fc2W, fc2b, out);
}

// Round 4
// 661.113 us; speedup vs baseline: 6.7108x; 1.0411x over previous
//
#include <hip/hip_runtime.h>
#include <math.h>

#define NNODES  100000
#define NEDGES  3200000
#define NGRAPHS 1024
#define NBLK    ((NNODES + 255) / 256)     // 391 scan blocks
#define NPART   8                          // one partition per XCD
#define PSTRIDE ((NNODES + NPART - 1) / NPART)   // 12500 nodes per partition
#define CHUNK   8192                       // edges per chunk
#define NCHUNKS ((NEDGES + CHUNK - 1) / CHUNK)   // 391

// ---------------- init ----------------

__global__ void zero4_kernel(int4* p, int nvec) {
    int i = blockIdx.x * blockDim.x + threadIdx.x;
    if (i < nvec) p[i] = make_int4(0, 0, 0, 0);
}

// dst-partitioned, XCD-pinned in-degree histogram
__global__ void hist_kernel(const int* __restrict__ dst, int* __restrict__ cnt) {
    int p = blockIdx.x & (NPART - 1);
    int c = blockIdx.x / NPART;
    int lo = p * PSTRIDE, hi = lo + PSTRIDE;
    int beg = c * CHUNK;
    int end = beg + CHUNK; if (end > NEDGES) end = NEDGES;
    for (int e = beg + threadIdx.x * 4; e < end; e += 256 * 4) {
        int4 d4 = *(const int4*)(dst + e);
        if (d4.x >= lo && d4.x < hi) atomicAdd(&cnt[d4.x], 1);
        if (d4.y >= lo && d4.y < hi) atomicAdd(&cnt[d4.y], 1);
        if (d4.z >= lo && d4.z < hi) atomicAdd(&cnt[d4.z], 1);
        if (d4.w >= lo && d4.w < hi) atomicAdd(&cnt[d4.w], 1);
    }
}

// dinv[n] = rsqrt(deg) and xs[n][f] = x[n][f] * dinv[n]  (thread per float4)
__global__ void dinvx_kernel(const int* __restrict__ cnt, const float4* __restrict__ x,
                             float* __restrict__ dinv, float4* __restrict__ xs) {
    int t = blockIdx.x * blockDim.x + threadIdx.x;
    if (t >= NNODES * 4) return;
    int n = t >> 2;
    float di = rsqrtf((float)(cnt[n] + 1));   // +1 self-loop
    if ((t & 3) == 0) dinv[n] = di;
    float4 v = x[t];
    v.x *= di; v.y *= di; v.z *= di; v.w *= di;
    xs[t] = v;
}

// ---------------- exclusive scan ----------------

__global__ void scanA_kernel(const int* __restrict__ cnt, int* __restrict__ part,
                             int* __restrict__ bsum) {
    __shared__ int s[256];
    int i = blockIdx.x * 256 + threadIdx.x;
    int v = (i < NNODES) ? cnt[i] : 0;
    s[threadIdx.x] = v;
    __syncthreads();
    for (int off = 1; off < 256; off <<= 1) {
        int t = (threadIdx.x >= off) ? s[threadIdx.x - off] : 0;
        __syncthreads();
        s[threadIdx.x] += t;
        __syncthreads();
    }
    int incl = s[threadIdx.x];
    if (i < NNODES) part[i] = incl - v;
    if (threadIdx.x == 255) bsum[blockIdx.x] = incl;
}

// single-wave scan over NBLK block sums
__global__ void scanB_kernel(const int* __restrict__ bsum, int* __restrict__ boff) {
    int lane = threadIdx.x;          // 64 lanes
    int run = 0;
    for (int base = 0; base < NBLK; base += 64) {
        int idx = base + lane;
        int own = (idx < NBLK) ? bsum[idx] : 0;
        int v = own;
        for (int off = 1; off < 64; off <<= 1) {
            int t = __shfl_up(v, off, 64);
            if (lane >= off) v += t;
        }
        if (idx < NBLK) boff[idx] = run + v - own;   // exclusive
        run += __shfl(v, 63, 64);
    }
}

__global__ void scanC_kernel(int* __restrict__ part, const int* __restrict__ boff,
                             int* __restrict__ rowptr, int* __restrict__ cursor) {
    int i = blockIdx.x * 256 + threadIdx.x;
    if (i < NNODES) {
        int v = part[i] + boff[blockIdx.x];
        rowptr[i] = v;
        cursor[i] = v;
    }
}

// ---------------- CSR fill (dst-partitioned, XCD-pinned, 4 B entries) ----------------

__global__ void csr_fill_kernel(const int* __restrict__ src, const int* __restrict__ dst,
                                int* __restrict__ cursor, int* __restrict__ entries) {
    int p = blockIdx.x & (NPART - 1);
    int c = blockIdx.x / NPART;
    int lo = p * PSTRIDE, hi = lo + PSTRIDE;
    int beg = c * CHUNK;
    int end = beg + CHUNK; if (end > NEDGES) end = NEDGES;
    for (int e = beg + threadIdx.x * 4; e < end; e += 256 * 4) {
        int4 d4 = *(const int4*)(dst + e);
        int4 s4 = *(const int4*)(src + e);
        if (d4.x >= lo && d4.x < hi) entries[atomicAdd(&cursor[d4.x], 1)] = s4.x;
        if (d4.y >= lo && d4.y < hi) entries[atomicAdd(&cursor[d4.y], 1)] = s4.y;
        if (d4.z >= lo && d4.z < hi) entries[atomicAdd(&cursor[d4.z], 1)] = s4.z;
        if (d4.w >= lo && d4.w < hi) entries[atomicAdd(&cursor[d4.w], 1)] = s4.w;
    }
}

// ---------------- gathers (chunked shfl-broadcast, norm-free) ----------------

// ax[n][f] = dinv[n] * (sum_in xs[src][f] + xs[n][f])   — 16 lanes/node
__global__ void gather1_kernel(const int* __restrict__ entries, const int* __restrict__ rowptr,
                               const int* __restrict__ rowend, const float* __restrict__ dinv,
                               const float* __restrict__ xs, float* __restrict__ ax) {
    int t = blockIdx.x * blockDim.x + threadIdx.x;
    int n = t >> 4, lane = t & 15;
    if (n >= NNODES) return;
    int beg = rowptr[n], end = rowend[n];
    float acc = xs[n * 16 + lane];   // self
    for (int base = beg; base < end; base += 16) {
        int m = end - base; if (m > 16) m = 16;
        int s = (lane < m) ? entries[base + lane] : 0;
        if (m == 16) {
#pragma unroll
            for (int j = 0; j < 16; ++j)
                acc += xs[__shfl(s, j, 16) * 16 + lane];
        } else {
            for (int j = 0; j < m; ++j)
                acc += xs[__shfl(s, j, 16) * 16 + lane];
        }
    }
    ax[n * 16 + lane] = acc * dinv[n];
}

// h2 then pool — 32 lanes/node
__global__ void gather2_pool_kernel(const int* __restrict__ entries, const int* __restrict__ rowptr,
                                    const int* __restrict__ rowend, const float* __restrict__ dinv,
                                    const float* __restrict__ hm2s, const float* __restrict__ b2,
                                    const int* __restrict__ batch,
                                    float* __restrict__ psum, float* __restrict__ pcnt) {
    int t = blockIdx.x * blockDim.x + threadIdx.x;
    int n = t >> 5, lane = t & 31;
    if (n >= NNODES) return;
    int beg = rowptr[n], end = rowend[n];
    float acc = hm2s[n * 32 + lane];   // self
    for (int base = beg; base < end; base += 32) {
        int m = end - base; if (m > 32) m = 32;
        int s = (lane < m) ? entries[base + lane] : 0;
        if (m == 32) {
#pragma unroll 16
            for (int j = 0; j < 32; ++j)
                acc += hm2s[__shfl(s, j, 32) * 32 + lane];
        } else {
            for (int j = 0; j < m; ++j)
                acc += hm2s[__shfl(s, j, 32) * 32 + lane];
        }
    }
    float v = fmaxf(acc * dinv[n] + b2[lane], 0.f);
    int g = batch[n];
    atomicAdd(&psum[g * 32 + lane], v);
    if (lane == 0) atomicAdd(&pcnt[g], 1.0f);
}

// ---------------- dense GEMMs ----------------

// h1 = relu(ax @ W1 + b1)
__global__ void gemm1_kernel(const float* __restrict__ ax, const float* __restrict__ W1,
                             const float* __restrict__ b1, float* __restrict__ h1) {
    __shared__ float w[16 * 64];
    __shared__ float bb[64];
    for (int i = threadIdx.x; i < 16 * 64; i += blockDim.x) w[i] = W1[i];
    if (threadIdx.x < 64) bb[threadIdx.x] = b1[threadIdx.x];
    __syncthreads();
    int t = blockIdx.x * blockDim.x + threadIdx.x;
    if (t >= NNODES * 64) return;
    int n = t >> 6, j = t & 63;
    const float* xr = ax + n * 16;
    float acc = bb[j];
#pragma unroll
    for (int k = 0; k < 16; ++k) acc += xr[k] * w[k * 64 + j];
    h1[t] = fmaxf(acc, 0.f);
}

// hm2s = (h1 @ W2) * dinv[n]
__global__ void gemm2_kernel(const float* __restrict__ h1, const float* __restrict__ W2,
                             const float* __restrict__ dinv, float* __restrict__ hm2s) {
    __shared__ float w[64 * 32];
    for (int i = threadIdx.x; i < 64 * 32; i += blockDim.x) w[i] = W2[i];
    __syncthreads();
    int t = blockIdx.x * blockDim.x + threadIdx.x;
    if (t >= NNODES * 32) return;
    int n = t >> 5, j = t & 31;
    const float* hr = h1 + n * 64;
    float acc = 0.f;
#pragma unroll
    for (int k = 0; k < 64; ++k) acc += hr[k] * w[k * 32 + j];
    hm2s[t] = acc * dinv[n];
}

// ---------------- head ----------------

__global__ void head_kernel(const float* __restrict__ psum, const float* __restrict__ pcnt,
                            const float* __restrict__ fc1W, const float* __restrict__ fc1b,
                            const float* __restrict__ fc2W, const float* __restrict__ fc2b,
                            float* __restrict__ out) {
    int g = blockIdx.x * blockDim.x + threadIdx.x;
    if (g >= NGRAPHS) return;
    float inv = 1.0f / fmaxf(pcnt[g], 1.0f);
    float gv[32];
#pragma unroll
    for (int k = 0; k < 32; ++k) gv[k] = psum[g * 32 + k] * inv;
    float o = fc2b[0];
#pragma unroll
    for (int j = 0; j < 16; ++j) {
        float h = fc1b[j];
#pragma unroll
        for (int k = 0; k < 32; ++k) h += gv[k] * fc1W[k * 16 + j];
        h = fmaxf(h, 0.f);
        o += h * fc2W[j];
    }
    out[g] = 1.0f / (1.0f + expf(-o));
}

// ---------------- launch ----------------

extern "C" void kernel_launch(void* const* d_in, const int* in_sizes, int n_in,
                              void* d_out, int out_size, void* d_ws, size_t ws_size,
                              hipStream_t stream) {
    const float* x    = (const float*)d_in[0];
    const int*   ei   = (const int*)d_in[1];
    const int*   batch= (const int*)d_in[2];
    const float* W1   = (const float*)d_in[3];
    const float* b1   = (const float*)d_in[4];
    const float* W2   = (const float*)d_in[5];
    const float* b2   = (const float*)d_in[6];
    const float* fc1W = (const float*)d_in[7];
    const float* fc1b = (const float*)d_in[8];
    const float* fc2W = (const float*)d_in[9];
    const float* fc2b = (const float*)d_in[10];
    float* out = (float*)d_out;

    const int* src = ei;
    const int* dst = ei + NEDGES;

    // workspace layout (512 B aligned blocks)
    char* wsb = (char*)d_ws;
    int*   cnt    = (int*)wsb;                 // 400000 B   } zeroed span
    float* psum   = (float*)(wsb + 400000);    // 131072 B   }
    float* pcnt   = (float*)(wsb + 531072);    // 4096 B     }
    float* dinv   = (float*)(wsb + 535552);    // 400000 B
    int*   rowptr = (int*)(wsb + 935936);      // 400000 B
    int*   cursor = (int*)(wsb + 1336320);     // 400000 B
    int*   bsum   = (int*)(wsb + 1736704);     // 1564 B
    int*   boff   = (int*)(wsb + 1738752);     // 1564 B
    int*   entries= (int*)(wsb + 1740800);     // 12.8 MB
    float* xs     = (float*)(wsb + 14541312);  // 6.4 MB
    float* ax     = (float*)(wsb + 20941824);  // 6.4 MB
    float* h1     = (float*)(wsb + 27342336);  // 25.6 MB
    float* hm2s   = (float*)(wsb + 52942848);  // 12.8 MB  (ends 65.7 MB)

    const int B = 256;
    // zero cnt+psum+pcnt: 535168 B = 33448 int4
    zero4_kernel<<<(33448 + B - 1) / B, B, 0, stream>>>((int4*)cnt, 33448);

    hist_kernel<<<NCHUNKS * NPART, B, 0, stream>>>(dst, cnt);
    dinvx_kernel<<<(NNODES * 4 + B - 1) / B, B, 0, stream>>>(cnt, (const float4*)x, dinv, (float4*)xs);

    scanA_kernel<<<NBLK, 256, 0, stream>>>(cnt, rowptr, bsum);
    scanB_kernel<<<1, 64, 0, stream>>>(bsum, boff);
    scanC_kernel<<<NBLK, 256, 0, stream>>>(rowptr, boff, rowptr, cursor);

    csr_fill_kernel<<<NCHUNKS * NPART, B, 0, stream>>>(src, dst, cursor, entries);

    gather1_kernel<<<(NNODES * 16 + B - 1) / B, B, 0, stream>>>(entries, rowptr, cursor, dinv, xs, ax);
    gemm1_kernel<<<(NNODES * 64 + B - 1) / B, B, 0, stream>>>(ax, W1, b1, h1);
    gemm2_kernel<<<(NNODES * 32 + B - 1) / B, B, 0, stream>>>(h1, W2, dinv, hm2s);
    gather2_pool_kernel<<<(NNODES * 32 + B - 1) / B, B, 0, stream>>>(entries, rowptr, cursor, dinv,
                                                                     hm2s, b2, batch, psum, pcnt);
    head_kernel<<<(NGRAPHS + B - 1) / B, B, 0, stream>>>(psum, pcnt, fc1W, fc1b, fc2W, fc2b, out);
}

// Round 5
// 576.118 us; speedup vs baseline: 7.7008x; 1.1475x over previous
//
#include <hip/hip_runtime.h>
#include <math.h>

#define NNODES  100000
#define NEDGES  3200000
#define NGRAPHS 1024
#define NBLK    ((NNODES + 255) / 256)     // 391 scan blocks
#define NPART   8                          // one partition per XCD
#define PSTRIDE ((NNODES + NPART - 1) / NPART)
#define CHUNK   8192
#define NCHUNKS ((NEDGES + CHUNK - 1) / CHUNK)   // 391

// ---- bf16x2 pack/unpack (RNE) ----
__device__ __forceinline__ unsigned bf16pair(float a, float b) {
    unsigned ua = __float_as_uint(a), ub = __float_as_uint(b);
    ua += 0x7fffu + ((ua >> 16) & 1u);
    ub += 0x7fffu + ((ub >> 16) & 1u);
    return (ua >> 16) | (ub & 0xffff0000u);
}
__device__ __forceinline__ float bflo(unsigned u) { return __uint_as_float(u << 16); }
__device__ __forceinline__ float bfhi(unsigned u) { return __uint_as_float(u & 0xffff0000u); }

// ---------------- init ----------------

__global__ void zero4_kernel(int4* p, int nvec) {
    int i = blockIdx.x * blockDim.x + threadIdx.x;
    if (i < nvec) p[i] = make_int4(0, 0, 0, 0);
}

// dst-partitioned, XCD-pinned in-degree histogram
__global__ void hist_kernel(const int* __restrict__ dst, int* __restrict__ cnt) {
    int p = blockIdx.x & (NPART - 1);
    int c = blockIdx.x / NPART;
    int lo = p * PSTRIDE, hi = lo + PSTRIDE;
    int beg = c * CHUNK;
    int end = beg + CHUNK; if (end > NEDGES) end = NEDGES;
    for (int e = beg + threadIdx.x * 4; e < end; e += 256 * 4) {
        int4 d4 = *(const int4*)(dst + e);
        if (d4.x >= lo && d4.x < hi) atomicAdd(&cnt[d4.x], 1);
        if (d4.y >= lo && d4.y < hi) atomicAdd(&cnt[d4.y], 1);
        if (d4.z >= lo && d4.z < hi) atomicAdd(&cnt[d4.z], 1);
        if (d4.w >= lo && d4.w < hi) atomicAdd(&cnt[d4.w], 1);
    }
}

// dinv[n]=rsqrt(deg+1); xs[n][f]=x[n][f]*dinv (bf16x2 packed) — thread per float4
__global__ void dinvx_kernel(const int* __restrict__ cnt, const float4* __restrict__ x,
                             float* __restrict__ dinv, unsigned* __restrict__ xs) {
    int t = blockIdx.x * blockDim.x + threadIdx.x;
    if (t >= NNODES * 4) return;
    int n = t >> 2, q = t & 3;
    float di = rsqrtf((float)(cnt[n] + 1));
    if (q == 0) dinv[n] = di;
    float4 v = x[t];
    unsigned p0 = bf16pair(v.x * di, v.y * di);
    unsigned p1 = bf16pair(v.z * di, v.w * di);
    xs[n * 8 + q * 2]     = p0;
    xs[n * 8 + q * 2 + 1] = p1;
}

// ---------------- exclusive scan ----------------

__global__ void scanA_kernel(const int* __restrict__ cnt, int* __restrict__ part,
                             int* __restrict__ bsum) {
    __shared__ int s[256];
    int i = blockIdx.x * 256 + threadIdx.x;
    int v = (i < NNODES) ? cnt[i] : 0;
    s[threadIdx.x] = v;
    __syncthreads();
    for (int off = 1; off < 256; off <<= 1) {
        int t = (threadIdx.x >= off) ? s[threadIdx.x - off] : 0;
        __syncthreads();
        s[threadIdx.x] += t;
        __syncthreads();
    }
    int incl = s[threadIdx.x];
    if (i < NNODES) part[i] = incl - v;
    if (threadIdx.x == 255) bsum[blockIdx.x] = incl;
}

__global__ void scanB_kernel(const int* __restrict__ bsum, int* __restrict__ boff) {
    int lane = threadIdx.x;          // 64 lanes
    int run = 0;
    for (int base = 0; base < NBLK; base += 64) {
        int idx = base + lane;
        int own = (idx < NBLK) ? bsum[idx] : 0;
        int v = own;
        for (int off = 1; off < 64; off <<= 1) {
            int t = __shfl_up(v, off, 64);
            if (lane >= off) v += t;
        }
        if (idx < NBLK) boff[idx] = run + v - own;
        run += __shfl(v, 63, 64);
    }
}

__global__ void scanC_kernel(int* __restrict__ part, const int* __restrict__ boff,
                             int* __restrict__ rowptr, int* __restrict__ cursor) {
    int i = blockIdx.x * 256 + threadIdx.x;
    if (i < NNODES) {
        int v = part[i] + boff[blockIdx.x];
        rowptr[i] = v;
        cursor[i] = v;
    }
}

// ---------------- CSR fill (dst-partitioned, XCD-pinned, 4 B entries) ----------------

__global__ void csr_fill_kernel(const int* __restrict__ src, const int* __restrict__ dst,
                                int* __restrict__ cursor, int* __restrict__ entries) {
    int p = blockIdx.x & (NPART - 1);
    int c = blockIdx.x / NPART;
    int lo = p * PSTRIDE, hi = lo + PSTRIDE;
    int beg = c * CHUNK;
    int end = beg + CHUNK; if (end > NEDGES) end = NEDGES;
    for (int e = beg + threadIdx.x * 4; e < end; e += 256 * 4) {
        int4 d4 = *(const int4*)(dst + e);
        int4 s4 = *(const int4*)(src + e);
        if (d4.x >= lo && d4.x < hi) entries[atomicAdd(&cursor[d4.x], 1)] = s4.x;
        if (d4.y >= lo && d4.y < hi) entries[atomicAdd(&cursor[d4.y], 1)] = s4.y;
        if (d4.z >= lo && d4.z < hi) entries[atomicAdd(&cursor[d4.z], 1)] = s4.z;
        if (d4.w >= lo && d4.w < hi) entries[atomicAdd(&cursor[d4.w], 1)] = s4.w;
    }
}

// ---------------- gather 1 (bf16, 8 lanes/node, 2 feats/lane) ----------------

__global__ void gather1_kernel(const int* __restrict__ entries, const int* __restrict__ rowptr,
                               const int* __restrict__ rowend, const float* __restrict__ dinv,
                               const unsigned* __restrict__ xs, unsigned* __restrict__ ax) {
    int t = blockIdx.x * blockDim.x + threadIdx.x;
    int n = t >> 3, lane = t & 7;
    int beg = rowptr[n], end = rowend[n];
    unsigned self = xs[n * 8 + lane];
    float a0 = bflo(self), a1 = bfhi(self);
    for (int base = beg; base < end; base += 8) {
        int m = end - base; if (m > 8) m = 8;
        int s = (lane < m) ? entries[base + lane] : 0;
        if (m == 8) {
#pragma unroll
            for (int j = 0; j < 8; ++j) {
                unsigned v = xs[__shfl(s, j, 8) * 8 + lane];
                a0 += bflo(v); a1 += bfhi(v);
            }
        } else {
            for (int j = 0; j < m; ++j) {
                unsigned v = xs[__shfl(s, j, 8) * 8 + lane];
                a0 += bflo(v); a1 += bfhi(v);
            }
        }
    }
    float di = dinv[n];
    ax[n * 8 + lane] = bf16pair(a0 * di, a1 * di);
}

// ---------------- fused node MLP: ax -> relu(axW1+b1) -> (h1W2)*dinv -> hm2s ----------------
// 16 nodes/block, 16 lanes/node

__global__ void mlp_kernel(const unsigned* __restrict__ axb, const float* __restrict__ W1,
                           const float* __restrict__ b1, const float* __restrict__ W2,
                           const float* __restrict__ dinv, unsigned* __restrict__ hm2s) {
    __shared__ float w1[16 * 64];
    __shared__ float w2[64 * 32];
    __shared__ float bb1[64];
    __shared__ float axs[16][17];   // +1 pad
    __shared__ float h1s[16][65];   // +1 pad
    int tid = threadIdx.x;
    for (int i = tid; i < 16 * 64; i += 256) w1[i] = W1[i];
    for (int i = tid; i < 64 * 32; i += 256) w2[i] = W2[i];
    if (tid < 64) bb1[tid] = b1[tid];

    int nl = tid >> 4, lane = tid & 15;
    int n = blockIdx.x * 16 + nl;

    if (lane < 8) {
        unsigned v = axb[n * 8 + lane];
        axs[nl][lane * 2]     = bflo(v);
        axs[nl][lane * 2 + 1] = bfhi(v);
    }
    __syncthreads();

    // phase B: h1[j] for j = lane*4 .. lane*4+3
    {
        int j0 = lane * 4;
        float h0 = bb1[j0], h1v = bb1[j0 + 1], h2 = bb1[j0 + 2], h3 = bb1[j0 + 3];
#pragma unroll
        for (int k = 0; k < 16; ++k) {
            float a = axs[nl][k];
            const float* wr = w1 + k * 64 + j0;
            h0 += a * wr[0]; h1v += a * wr[1]; h2 += a * wr[2]; h3 += a * wr[3];
        }
        h1s[nl][j0]     = fmaxf(h0, 0.f);
        h1s[nl][j0 + 1] = fmaxf(h1v, 0.f);
        h1s[nl][j0 + 2] = fmaxf(h2, 0.f);
        h1s[nl][j0 + 3] = fmaxf(h3, 0.f);
    }
    __syncthreads();

    // phase C: hm2[j] for j = lane*2, lane*2+1
    {
        int j0 = lane * 2;
        float c0 = 0.f, c1 = 0.f;
#pragma unroll
        for (int k = 0; k < 64; ++k) {
            float hv = h1s[nl][k];
            c0 += hv * w2[k * 32 + j0];
            c1 += hv * w2[k * 32 + j0 + 1];
        }
        float di = dinv[n];
        hm2s[n * 16 + lane] = bf16pair(c0 * di, c1 * di);
    }
}

// ---------------- gather 2 + pool (bf16, 16 lanes/node, 2 feats/lane) ----------------

__global__ void gather2_pool_kernel(const int* __restrict__ entries, const int* __restrict__ rowptr,
                                    const int* __restrict__ rowend, const float* __restrict__ dinv,
                                    const unsigned* __restrict__ hm2s, const float* __restrict__ b2,
                                    const int* __restrict__ batch,
                                    float* __restrict__ psum, float* __restrict__ pcnt) {
    int t = blockIdx.x * blockDim.x + threadIdx.x;
    int n = t >> 4, lane = t & 15;
    int beg = rowptr[n], end = rowend[n];
    unsigned self = hm2s[n * 16 + lane];
    float a0 = bflo(self), a1 = bfhi(self);
    for (int base = beg; base < end; base += 16) {
        int m = end - base; if (m > 16) m = 16;
        int s = (lane < m) ? entries[base + lane] : 0;
        if (m == 16) {
#pragma unroll
            for (int j = 0; j < 16; ++j) {
                unsigned v = hm2s[__shfl(s, j, 16) * 16 + lane];
                a0 += bflo(v); a1 += bfhi(v);
            }
        } else {
            for (int j = 0; j < m; ++j) {
                unsigned v = hm2s[__shfl(s, j, 16) * 16 + lane];
                a0 += bflo(v); a1 += bfhi(v);
            }
        }
    }
    float di = dinv[n];
    int j0 = lane * 2;
    float v0 = fmaxf(a0 * di + b2[j0], 0.f);
    float v1 = fmaxf(a1 * di + b2[j0 + 1], 0.f);
    int g = batch[n];
    atomicAdd(&psum[g * 32 + j0], v0);
    atomicAdd(&psum[g * 32 + j0 + 1], v1);
    if (lane == 0) atomicAdd(&pcnt[g], 1.0f);
}

// ---------------- head ----------------

__global__ void head_kernel(const float* __restrict__ psum, const float* __restrict__ pcnt,
                            const float* __restrict__ fc1W, const float* __restrict__ fc1b,
                            const float* __restrict__ fc2W, const float* __restrict__ fc2b,
                            float* __restrict__ out) {
    int g = blockIdx.x * blockDim.x + threadIdx.x;
    if (g >= NGRAPHS) return;
    float inv = 1.0f / fmaxf(pcnt[g], 1.0f);
    float gv[32];
#pragma unroll
    for (int k = 0; k < 32; ++k) gv[k] = psum[g * 32 + k] * inv;
    float o = fc2b[0];
#pragma unroll
    for (int j = 0; j < 16; ++j) {
        float h = fc1b[j];
#pragma unroll
        for (int k = 0; k < 32; ++k) h += gv[k] * fc1W[k * 16 + j];
        h = fmaxf(h, 0.f);
        o += h * fc2W[j];
    }
    out[g] = 1.0f / (1.0f + expf(-o));
}

// ---------------- launch ----------------

extern "C" void kernel_launch(void* const* d_in, const int* in_sizes, int n_in,
                              void* d_out, int out_size, void* d_ws, size_t ws_size,
                              hipStream_t stream) {
    const float* x    = (const float*)d_in[0];
    const int*   ei   = (const int*)d_in[1];
    const int*   batch= (const int*)d_in[2];
    const float* W1   = (const float*)d_in[3];
    const float* b1   = (const float*)d_in[4];
    const float* W2   = (const float*)d_in[5];
    const float* b2   = (const float*)d_in[6];
    const float* fc1W = (const float*)d_in[7];
    const float* fc1b = (const float*)d_in[8];
    const float* fc2W = (const float*)d_in[9];
    const float* fc2b = (const float*)d_in[10];
    float* out = (float*)d_out;

    const int* src = ei;
    const int* dst = ei + NEDGES;

    char* wsb = (char*)d_ws;
    int*      cnt    = (int*)wsb;                 // 400000 B  } zeroed span
    float*    psum   = (float*)(wsb + 400000);    // 131072 B  }
    float*    pcnt   = (float*)(wsb + 531072);    // 4096 B    }
    float*    dinv   = (float*)(wsb + 535552);    // 400000 B
    int*      rowptr = (int*)(wsb + 935936);      // 400000 B
    int*      cursor = (int*)(wsb + 1336320);     // 400000 B
    int*      bsum   = (int*)(wsb + 1736704);     // ~2 KB
    int*      boff   = (int*)(wsb + 1738752);     // ~2 KB
    int*      entries= (int*)(wsb + 1740800);     // 12.8 MB
    unsigned* xs     = (unsigned*)(wsb + 14541312);  // 3.2 MB  (bf16x2)
    unsigned* ax     = (unsigned*)(wsb + 17741312);  // 3.2 MB
    unsigned* hm2s   = (unsigned*)(wsb + 20941312);  // 6.4 MB  (ends ~27.4 MB)

    const int B = 256;
    zero4_kernel<<<(33448 + B - 1) / B, B, 0, stream>>>((int4*)cnt, 33448);

    hist_kernel<<<NCHUNKS * NPART, B, 0, stream>>>(dst, cnt);
    dinvx_kernel<<<(NNODES * 4 + B - 1) / B, B, 0, stream>>>(cnt, (const float4*)x, dinv, xs);

    scanA_kernel<<<NBLK, 256, 0, stream>>>(cnt, rowptr, bsum);
    scanB_kernel<<<1, 64, 0, stream>>>(bsum, boff);
    scanC_kernel<<<NBLK, 256, 0, stream>>>(rowptr, boff, rowptr, cursor);

    csr_fill_kernel<<<NCHUNKS * NPART, B, 0, stream>>>(src, dst, cursor, entries);

    gather1_kernel<<<NNODES * 8 / B, B, 0, stream>>>(entries, rowptr, cursor, dinv, xs, ax);
    mlp_kernel<<<NNODES / 16, B, 0, stream>>>(ax, W1, b1, W2, dinv, hm2s);
    gather2_pool_kernel<<<NNODES * 16 / B, B, 0, stream>>>(entries, rowptr, cursor, dinv,
                                                           hm2s, b2, batch, psum, pcnt);
    head_kernel<<<(NGRAPHS + B - 1) / B, B, 0, stream>>>(psum, pcnt, fc1W, fc1b, fc2W, fc2b, out);
}